// Round 2
// 1327.536 us; speedup vs baseline: 1.1152x; 1.1152x over previous
//
#include <hip/hip_runtime.h>
#include <stdint.h>

#define DIM 1536
#define NHEADS 12
#define HD 128
#define FFN 8960
#define SQ 3456
#define T5 512
#define LCTX 769
#define IMG 257
#define IMGP 384
#define EPSL 1e-6f

typedef __bf16 bf16;
typedef __bf16 bf16x8 __attribute__((ext_vector_type(8)));
typedef float f32x4 __attribute__((ext_vector_type(4)));

__device__ inline bf16x8 zero_bf16x8() {
  bf16x8 v;
  for (int i = 0; i < 8; i++) v[i] = (bf16)0.0f;
  return v;
}

// async 16B global -> LDS. lds base must be wave-uniform; lane i lands at lds + i*16.
__device__ inline void glds16(const bf16* g, bf16* lds) {
  __builtin_amdgcn_global_load_lds(
      (const __attribute__((address_space(1))) void*)g,
      (__attribute__((address_space(3))) void*)lds, 16, 0, 0);
}

// rotate bf16x8 left by r elements: out[i] = v[(i+r)&7]. All compile-time vector
// subscripts (runtime subscripts spill to scratch); selects become v_cndmask,
// 1-element stage is v_alignbit.
__device__ inline bf16x8 rot8(bf16x8 v, int r) {
  union U { bf16x8 b; uint32_t d[4]; };
  U u; u.b = v;
  uint32_t e0 = (r & 4) ? u.d[2] : u.d[0], e1 = (r & 4) ? u.d[3] : u.d[1];
  uint32_t e2 = (r & 4) ? u.d[0] : u.d[2], e3 = (r & 4) ? u.d[1] : u.d[3];
  uint32_t f0 = (r & 2) ? e1 : e0, f1 = (r & 2) ? e2 : e1;
  uint32_t f2 = (r & 2) ? e3 : e2, f3 = (r & 2) ? e0 : e3;
  U o;
  o.d[0] = (r & 1) ? __builtin_amdgcn_alignbit(f1, f0, 16) : f0;
  o.d[1] = (r & 1) ? __builtin_amdgcn_alignbit(f2, f1, 16) : f1;
  o.d[2] = (r & 1) ? __builtin_amdgcn_alignbit(f3, f2, 16) : f2;
  o.d[3] = (r & 1) ? __builtin_amdgcn_alignbit(f0, f3, 16) : f3;
  return o.b;
}

// ---------------- small utility kernels ----------------

__global__ void prep_small_kernel(const float* __restrict__ modv, const float* __restrict__ e,
                                  float* __restrict__ e6f,
                                  const float* __restrict__ qb, const float* __restrict__ kb,
                                  const float* __restrict__ vb, float* __restrict__ qkvB,
                                  const float* __restrict__ ckb, const float* __restrict__ cvb,
                                  float* __restrict__ kvB,
                                  const float* __restrict__ kib, const float* __restrict__ vib,
                                  float* __restrict__ kivB) {
  int i = blockIdx.x * 256 + threadIdx.x;
  if (i < 6 * DIM) e6f[i] = modv[i] + e[i];
  if (i < DIM) {
    qkvB[i] = qb[i]; qkvB[i + DIM] = kb[i]; qkvB[i + 2 * DIM] = vb[i];
    kvB[i] = ckb[i]; kvB[i + DIM] = cvb[i];
    kivB[i] = kib[i]; kivB[i + DIM] = vib[i];
  }
}

// context -> bf16: txt rows 257..768 -> ctxt[512], img rows 0..256 -> ctxi[384] zero-padded
__global__ void prep_ctx_kernel(const float* __restrict__ ctx, bf16* __restrict__ ctxt,
                                bf16* __restrict__ ctxi) {
  int i = blockIdx.x * 256 + threadIdx.x;
  if (i < T5 * DIM) ctxt[i] = (bf16)ctx[(size_t)IMG * DIM + i];
  if (i < IMGP * DIM) {
    int r = i / DIM;
    ctxi[i] = (r < IMG) ? (bf16)ctx[i] : (bf16)0.0f;
  }
}

// transpose up to 3 weights W (K x N, f32) -> Wt (N x K, bf16), z selects source/dest slot.
__global__ void transpose_w3_kernel(const float* __restrict__ W0, const float* __restrict__ W1,
                                    const float* __restrict__ W2, bf16* __restrict__ Wt,
                                    int K, int N) {
  __shared__ float tile[32][33];
  const float* W = blockIdx.z == 0 ? W0 : (blockIdx.z == 1 ? W1 : W2);
  bf16* dst = Wt + (size_t)blockIdx.z * K * N;
  int n0 = blockIdx.x * 32, k0 = blockIdx.y * 32;
  int tx = threadIdx.x, ty = threadIdx.y;  // block (32,8)
  for (int i = ty; i < 32; i += 8)
    tile[i][tx] = W[(size_t)(k0 + i) * N + n0 + tx];
  __syncthreads();
  for (int i = ty; i < 32; i += 8)
    dst[(size_t)(n0 + i) * K + k0 + tx] = (bf16)tile[tx][i];
}

// block=256, two-value sum reduction broadcast to all threads
__device__ inline void block_reduce2(float& s1, float& s2) {
  __shared__ float buf[8];
  for (int off = 32; off; off >>= 1) {
    s1 += __shfl_down(s1, off, 64);
    s2 += __shfl_down(s2, off, 64);
  }
  int w = threadIdx.x >> 6;
  if ((threadIdx.x & 63) == 0) { buf[w] = s1; buf[w + 4] = s2; }
  __syncthreads();
  s1 = buf[0] + buf[1] + buf[2] + buf[3];
  s2 = buf[4] + buf[5] + buf[6] + buf[7];
  __syncthreads();
}

// y = LN(x) * (gamma (+1?)) + beta ; one block per row
__global__ __launch_bounds__(256) void ln_mod_kernel(
    const float* __restrict__ X, const float* __restrict__ gamma,
    const float* __restrict__ beta, int plus_one, bf16* __restrict__ out) {
  int r = blockIdx.x;
  const float* xr = X + (size_t)r * DIM;
  float v[6], s = 0.f, s2 = 0.f;
  for (int i = 0; i < 6; i++) {
    v[i] = xr[threadIdx.x + i * 256];
    s += v[i]; s2 += v[i] * v[i];
  }
  block_reduce2(s, s2);
  float mean = s * (1.0f / DIM);
  float var = s2 * (1.0f / DIM) - mean * mean;
  float rstd = rsqrtf(var + EPSL);
  float add1 = plus_one ? 1.0f : 0.0f;
  for (int i = 0; i < 6; i++) {
    int c = threadIdx.x + i * 256;
    out[(size_t)r * DIM + c] = (bf16)(((v[i] - mean) * rstd) * (gamma[c] + add1) + beta[c]);
  }
}

// fused per-row postprocess of a GEMM f32 output with row stride `istride`:
// blockIdx.y = section; per section: mode 0=cast, 1=rms, 2=rms+rope
__global__ __launch_bounds__(256) void rms_rope_multi_kernel(
    const float* __restrict__ X, int istride, int nsec,
    const float* __restrict__ nw0, const float* __restrict__ nw1,
    int mode0, int mode1, int mode2,
    const float* __restrict__ freqs,
    bf16* __restrict__ o0, bf16* __restrict__ o1, bf16* __restrict__ o2) {
  int sec = blockIdx.y;
  int r = blockIdx.x;
  const float* xr = X + (size_t)r * istride + sec * DIM;
  const float* nw = sec == 0 ? nw0 : nw1;
  bf16* out = (sec == 0 ? o0 : (sec == 1 ? o1 : o2)) + (size_t)r * DIM;
  int mode = sec == 0 ? mode0 : (sec == 1 ? mode1 : mode2);
  float v[6];
  for (int i = 0; i < 6; i++) v[i] = xr[threadIdx.x + i * 256];
  if (mode == 0) {
    for (int i = 0; i < 6; i++) out[threadIdx.x + i * 256] = (bf16)v[i];
    return;
  }
  float s2 = 0.f, dummy = 0.f;
  for (int i = 0; i < 6; i++) s2 += v[i] * v[i];
  block_reduce2(s2, dummy);
  float rms = rsqrtf(s2 * (1.0f / DIM) + EPSL);
  if (mode == 1) {
    for (int i = 0; i < 6; i++) {
      int c = threadIdx.x + i * 256;
      out[c] = (bf16)(v[i] * rms * nw[c]);
    }
  } else {
    int f = r / (18 * 24), rem = r % (18 * 24), hh = rem / 24, ww = rem % 24;
    for (int i = 0; i < 3; i++) {
      int p = threadIdx.x + i * 256;  // pair index
      int id = p & 63;
      int idx = id < 22 ? f : (id < 43 ? hh : ww);
      float th = freqs[idx * 64 + id];
      float cs = __cosf(th), sn = __sinf(th);
      float re = xr[2 * p] * rms * nw[2 * p];
      float im = xr[2 * p + 1] * rms * nw[2 * p + 1];
      out[2 * p]     = (bf16)(re * cs - im * sn);
      out[2 * p + 1] = (bf16)(re * sn + im * cs);
    }
  }
}

// FFN2 split-K reduce: out = xcur + (p0 + p1 + b2[col]) * e5[col]
__global__ void ffn2_reduce_kernel(const float* __restrict__ p, const float* __restrict__ b2,
                                   const float* __restrict__ e5, const float* __restrict__ xcur,
                                   float* __restrict__ out) {
  int i = blockIdx.x * 256 + threadIdx.x;
  if (i >= SQ * DIM) return;
  int col = i % DIM;
  out[i] = xcur[i] + (p[i] + p[i + (size_t)SQ * DIM] + b2[col]) * e5[col];
}

// ---------------- GEMM: C[M,N] = A[M,K](bf16) @ Wt[N,K]^T + epilogue ----------------
template <int BM>
__global__ __launch_bounds__(256) void gemm_db_kernel(
    const bf16* __restrict__ A, const bf16* __restrict__ Wt,
    const float* __restrict__ bias, const float* __restrict__ scalev,
    const float* __restrict__ resid, float* __restrict__ outF,
    bf16* __restrict__ outB, int M, int N, int K, int gelu, int ksplit) {
  constexpr int MI = BM / 32;
  constexpr int NAW = BM / 64;  // A glds per wave
  __shared__ bf16 As[2][BM * 32];
  __shared__ bf16 Bs[2][128 * 32];
  int tid = threadIdx.x;
  int tm0 = blockIdx.y * BM, tn0 = blockIdx.x * 128;
  int lane = tid & 63, wave = tid >> 6;
  int quad = lane >> 4, l16 = lane & 15;
  int mbase = (wave >> 1) * (BM / 2), nbase = (wave & 1) * 64;
  int lrow = lane >> 2, lcol = (lane & 3) * 8;
  int klen = K / ksplit;
  int kbeg = blockIdx.z * klen;

  const bf16* aP[NAW];
  const bf16* bP[2];
#pragma unroll
  for (int j = 0; j < NAW; j++) {
    int c = wave * NAW + j;
    aP[j] = A + (size_t)(tm0 + c * 16 + lrow) * K + kbeg + lcol;
  }
#pragma unroll
  for (int j = 0; j < 2; j++) {
    int c = wave * 2 + j;
    bP[j] = Wt + (size_t)(tn0 + c * 16 + lrow) * K + kbeg + lcol;
  }

  f32x4 acc[MI][4];
#pragma unroll
  for (int mi = 0; mi < MI; mi++)
    for (int ni = 0; ni < 4; ni++)
      for (int rr = 0; rr < 4; rr++) acc[mi][ni][rr] = 0.0f;

  auto stage = [&](int buf) {
#pragma unroll
    for (int j = 0; j < NAW; j++) {
      glds16(aP[j], &As[buf][(wave * NAW + j) * 512]);
      aP[j] += 32;
    }
#pragma unroll
    for (int j = 0; j < 2; j++) {
      glds16(bP[j], &Bs[buf][(wave * 2 + j) * 512]);
      bP[j] += 32;
    }
  };

  int niter = klen / 32;
  stage(0);
  int cur = 0;
  for (int it = 0; it < niter; it++) {
    __syncthreads();               // drains vmcnt: tile `cur` resident in LDS
    if (it + 1 < niter) stage(cur ^ 1);  // prefetch overlaps compute below
    bf16x8 af[MI], bfr[4];
#pragma unroll
    for (int mi = 0; mi < MI; mi++)
      af[mi] = *(bf16x8*)&As[cur][(mbase + mi * 16 + l16) * 32 + quad * 8];
#pragma unroll
    for (int ni = 0; ni < 4; ni++)
      bfr[ni] = *(bf16x8*)&Bs[cur][(nbase + ni * 16 + l16) * 32 + quad * 8];
#pragma unroll
    for (int mi = 0; mi < MI; mi++)
#pragma unroll
      for (int ni = 0; ni < 4; ni++)
        acc[mi][ni] = __builtin_amdgcn_mfma_f32_16x16x32_bf16(af[mi], bfr[ni], acc[mi][ni], 0, 0, 0);
    cur ^= 1;
  }

  if (ksplit > 1) {
    float* po = outF + (size_t)blockIdx.z * M * N;
#pragma unroll
    for (int mi = 0; mi < MI; mi++) {
      int rbase = tm0 + mbase + mi * 16 + quad * 4;
#pragma unroll
      for (int ni = 0; ni < 4; ni++) {
        int col = tn0 + nbase + ni * 16 + l16;
        for (int rr = 0; rr < 4; rr++)
          po[(size_t)(rbase + rr) * N + col] = acc[mi][ni][rr];
      }
    }
    return;
  }

#pragma unroll
  for (int mi = 0; mi < MI; mi++) {
    int rbase = tm0 + mbase + mi * 16 + quad * 4;
#pragma unroll
    for (int ni = 0; ni < 4; ni++) {
      int col = tn0 + nbase + ni * 16 + l16;
      float b = bias ? bias[col] : 0.0f;
      float sc = scalev ? scalev[col] : 1.0f;
      for (int rr = 0; rr < 4; rr++) {
        int row = rbase + rr;
        float t = acc[mi][ni][rr] + b;
        if (gelu) {
          float z = t;
          float u = 0.7978845608028654f * (z + 0.044715f * z * z * z);
          t = z / (1.0f + __expf(-2.0f * u));  // == 0.5z(1+tanh(u))
        }
        t *= sc;
        size_t idx = (size_t)row * N + col;
        if (resid) t += resid[idx];
        if (outF) outF[idx] = t;
        else outB[idx] = (bf16)t;
      }
    }
  }
}

// ---------------- Flash attention, K-split partials ----------------
// Each block: 64 q-rows x one head x one K-chunk [bz*kchunk, min(L, ..+kchunk)).
// Writes normalized partial O (f32) to Opart[zabs] and per-row (m,l) to mlb.
// Conflict fixes: rotated V-transpose writes (was 16-way -> 2-way),
// XOR-swizzled Ps (was 4-way -> 2-way). Barrier count 3 -> 2 per tile
// (Ps is per-wave: lgkmcnt ordering suffices). Next K/V tile prefetched into
// registers right after staging so HBM latency hides under QK+softmax+PV.
__global__ __launch_bounds__(256) void attn_kernel(
    const bf16* __restrict__ Q, const bf16* __restrict__ Kb, const bf16* __restrict__ Vb,
    float* __restrict__ Opart, float* __restrict__ mlb,
    int L, int kchunk, int zoff) {
  __shared__ bf16 Ks[32][136];
  __shared__ bf16 Vts[128][40];
  __shared__ bf16 Ps[4][16][40];

  // XCD-contiguity swizzle: group q-blocks of the same (head, split) on one XCD
  // so they share the K/V chunk in that XCD's L2. Bijective when nwg % 8 == 0
  // (1944 / 1296 / 648 all are).
  int nwg = gridDim.x * gridDim.y * gridDim.z;
  int flat = blockIdx.x + gridDim.x * (blockIdx.y + gridDim.y * blockIdx.z);
  if ((nwg & 7) == 0) flat = (flat & 7) * (nwg >> 3) + (flat >> 3);
  int bx = flat % gridDim.x;
  int rest = flat / gridDim.x;
  int hb = rest % gridDim.y;
  int bz = rest / gridDim.y;

  int tid = threadIdx.x;
  int q0 = bx * 64;
  int zabs = zoff + bz;
  int kbeg = bz * kchunk;
  int kend = min(L, kbeg + kchunk);
  int klen = kend - kbeg;
  int lane = tid & 63, wave = tid >> 6;
  int quad = lane >> 4, l16 = lane & 15;
  int qrow = q0 + wave * 16 + l16;

  bf16x8 qf[4];
#pragma unroll
  for (int c = 0; c < 4; c++)
    qf[c] = *(const bf16x8*)(Q + (size_t)qrow * DIM + hb * HD + c * 32 + quad * 8);

  f32x4 o[8];
#pragma unroll
  for (int ff = 0; ff < 8; ff++)
    for (int rr = 0; rr < 4; rr++) o[ff][rr] = 0.0f;
  float m_i[4], l_i[4];
#pragma unroll
  for (int r = 0; r < 4; r++) { m_i[r] = -1e30f; l_i[r] = 0.0f; }
  const float sc = 0.08838834764831845f;  // 1/sqrt(128)

  int srow = tid >> 3, scolc = tid & 7, scol = scolc * 16;
  int nt = (klen + 31) / 32;

  const bf16* kp0 = Kb + (size_t)(kbeg + srow) * DIM + hb * HD + scol;
  const bf16* vp0 = Vb + (size_t)(kbeg + srow) * DIM + hb * HD + scol;

  bf16x8 k0v, k1v, v0v, v1v;
  if (srow < klen) {
    k0v = *(const bf16x8*)kp0; k1v = *(const bf16x8*)(kp0 + 8);
    v0v = *(const bf16x8*)vp0; v1v = *(const bf16x8*)(vp0 + 8);
  } else {
    k0v = zero_bf16x8(); k1v = zero_bf16x8();
    v0v = zero_bf16x8(); v1v = zero_bf16x8();
  }

  for (int kt = 0; kt < nt; kt++) {
    __syncthreads();  // prev tile's LDS readers done
    *(bf16x8*)&Ks[srow][scol] = k0v;
    *(bf16x8*)&Ks[srow][scol + 8] = k1v;
    {
      // rotated write order: bank = jj*20 + srow>>1 (mod 32), jj distinct per
      // scolc -> all 32 banks covered, 2 lanes each (free).
      bf16x8 r0 = rot8(v0v, scolc), r1 = rot8(v1v, scolc);
#pragma unroll
      for (int i = 0; i < 8; i++) {
        int jj = (i + scolc) & 7;
        Vts[scol + jj][srow] = r0[i];
        Vts[scol + 8 + jj][srow] = r1[i];
      }
    }
    // prefetch next tile into registers; consumed after next loop-top barrier
    if (kt + 1 < nt) {
      int key = (kt + 1) * 32 + srow;
      const bf16* kp = kp0 + (size_t)(kt + 1) * 32 * DIM;
      const bf16* vp = vp0 + (size_t)(kt + 1) * 32 * DIM;
      if (key < klen) {
        k0v = *(const bf16x8*)kp; k1v = *(const bf16x8*)(kp + 8);
        v0v = *(const bf16x8*)vp; v1v = *(const bf16x8*)(vp + 8);
      } else {
        k0v = zero_bf16x8(); k1v = zero_bf16x8();
        v0v = zero_bf16x8(); v1v = zero_bf16x8();
      }
    }
    __syncthreads();  // staged tile visible

    f32x4 sfr[2];
    __builtin_amdgcn_s_setprio(1);
#pragma unroll
    for (int nf = 0; nf < 2; nf++) {
      f32x4 a;
      for (int rr = 0; rr < 4; rr++) a[rr] = 0.0f;
#pragma unroll
      for (int c = 0; c < 4; c++) {
        bf16x8 kf = *(bf16x8*)&Ks[nf * 16 + l16][c * 32 + quad * 8];
        a = __builtin_amdgcn_mfma_f32_16x16x32_bf16(qf[c], kf, a, 0, 0, 0);
      }
      sfr[nf] = a;
    }
    __builtin_amdgcn_s_setprio(0);

#pragma unroll
    for (int nf = 0; nf < 2; nf++) {
      int colg = kt * 32 + nf * 16 + l16;
      bool valid = colg < klen;
#pragma unroll
      for (int r = 0; r < 4; r++)
        sfr[nf][r] = valid ? sfr[nf][r] * sc : -1e30f;
    }
    float mnew[4], alpha[4];
#pragma unroll
    for (int r = 0; r < 4; r++) {
      float t = fmaxf(sfr[0][r], sfr[1][r]);
#pragma unroll
      for (int off = 1; off < 16; off <<= 1) t = fmaxf(t, __shfl_xor(t, off, 64));
      mnew[r] = fmaxf(m_i[r], t);
      alpha[r] = __expf(m_i[r] - mnew[r]);
      m_i[r] = mnew[r];
    }
#pragma unroll
    for (int r = 0; r < 4; r++) {
      float p0 = __expf(sfr[0][r] - mnew[r]);
      float p1 = __expf(sfr[1][r] - mnew[r]);
      // XOR swizzle: physical colbyte = logical ^ ((row>>2)<<4); row = quad*4+r
      char* prow = (char*)&Ps[wave][quad * 4 + r][0];
      *(bf16*)(prow + ((l16 * 2) ^ (quad << 4))) = (bf16)p0;
      *(bf16*)(prow + ((32 + l16 * 2) ^ (quad << 4))) = (bf16)p1;
      float t = p0 + p1;
#pragma unroll
      for (int off = 1; off < 16; off <<= 1) t += __shfl_xor(t, off, 64);
      l_i[r] = l_i[r] * alpha[r] + t;
#pragma unroll
      for (int ff = 0; ff < 8; ff++) o[ff][r] *= alpha[r];
    }
    // no barrier: Ps is per-wave; compiler's lgkmcnt orders write->read
    bf16x8 pf = *(bf16x8*)((char*)&Ps[wave][l16][0] + ((quad * 16) ^ ((l16 >> 2) << 4)));
    __builtin_amdgcn_s_setprio(1);
#pragma unroll
    for (int ff = 0; ff < 8; ff++) {
      bf16x8 vf = *(bf16x8*)&Vts[ff * 16 + l16][quad * 8];
      o[ff] = __builtin_amdgcn_mfma_f32_16x16x32_bf16(pf, vf, o[ff], 0, 0, 0);
    }
    __builtin_amdgcn_s_setprio(0);
  }

  float* po = Opart + (size_t)zabs * SQ * DIM;
#pragma unroll
  for (int r = 0; r < 4; r++) {
    float inv = 1.0f / l_i[r];
#pragma unroll
    for (int ff = 0; ff < 8; ff++) o[ff][r] *= inv;
  }
#pragma unroll
  for (int ff = 0; ff < 8; ff++) {
#pragma unroll
    for (int r = 0; r < 4; r++) {
      int row = q0 + wave * 16 + quad * 4 + r;
      int col = hb * HD + ff * 16 + l16;
      po[(size_t)row * DIM + col] = o[ff][r];
    }
  }
  if (l16 == 0) {
#pragma unroll
    for (int r = 0; r < 4; r++) {
      int row = q0 + wave * 16 + quad * 4 + r;
      size_t mi = (((size_t)zabs * NHEADS + hb) * SQ + row) * 2;
      mlb[mi] = m_i[r];
      mlb[mi + 1] = l_i[r];
    }
  }
}

// Combine partial attention outputs.
// Slots [0, nmerge) are flash-decoding partials of ONE softmax -> merged with
// weights w_z = l_z*exp(m_z-M)/sum. If addslot >= 0, that slot is a SEPARATE,
// already-normalized attention output that is ADDED (reference cross-attn is
// softmax(txt) + softmax(img), NOT a softmax over the union).
__global__ __launch_bounds__(256) void attn_combine_kernel(
    const float* __restrict__ Op, const float* __restrict__ mlb,
    bf16* __restrict__ out, int nmerge, int addslot) {
  int row = blockIdx.x;
  __shared__ float wsh[3 * NHEADS];
  int t = threadIdx.x;
  if (t < NHEADS) {
    float m[3], l[3];
    for (int z = 0; z < 3; z++) {
      if (z < nmerge) {
        size_t b = (((size_t)z * NHEADS + t) * SQ + row) * 2;
        m[z] = mlb[b]; l[z] = mlb[b + 1];
      } else {
        m[z] = -1e30f; l[z] = 0.0f;
      }
    }
    float M = fmaxf(m[0], fmaxf(m[1], m[2]));
    float w0 = l[0] * __expf(m[0] - M);
    float w1 = l[1] * __expf(m[1] - M);
    float w2 = l[2] * __expf(m[2] - M);
    float inv = 1.0f / (w0 + w1 + w2);
    wsh[t] = w0 * inv;
    wsh[NHEADS + t] = w1 * inv;
    wsh[2 * NHEADS + t] = w2 * inv;
  }
  __syncthreads();
#pragma unroll
  for (int i = 0; i < 6; i++) {
    int c = t + i * 256;
    int h = c >> 7;
    float acc = wsh[h] * Op[((size_t)0 * SQ + row) * DIM + c];
    if (nmerge > 1) acc += wsh[NHEADS + h] * Op[((size_t)1 * SQ + row) * DIM + c];
    if (nmerge > 2) acc += wsh[2 * NHEADS + h] * Op[((size_t)2 * SQ + row) * DIM + c];
    if (addslot >= 0) acc += Op[((size_t)addslot * SQ + row) * DIM + c];
    out[(size_t)row * DIM + c] = (bf16)acc;
  }
}

// ---------------- host orchestration ----------------

extern "C" void kernel_launch(void* const* d_in, const int* in_sizes, int n_in,
                              void* d_out, int out_size, void* d_ws, size_t ws_size,
                              hipStream_t stream) {
  const float* x      = (const float*)d_in[0];
  const float* e      = (const float*)d_in[1];
  const float* ctx    = (const float*)d_in[2];
  const float* freqs  = (const float*)d_in[3];
  const float* modv   = (const float*)d_in[4];
  const float* sa_qw  = (const float*)d_in[5];
  const float* sa_qb  = (const float*)d_in[6];
  const float* sa_kw  = (const float*)d_in[7];
  const float* sa_kb  = (const float*)d_in[8];
  const float* sa_vw  = (const float*)d_in[9];
  const float* sa_vb  = (const float*)d_in[10];
  const float* sa_ow  = (const float*)d_in[11];
  const float* sa_ob  = (const float*)d_in[12];
  const float* sa_nq  = (const float*)d_in[13];
  const float* sa_nk  = (const float*)d_in[14];
  const float* norm3w = (const float*)d_in[15];
  const float* norm3b = (const float*)d_in[16];
  const float* ca_qw  = (const float*)d_in[17];
  const float* ca_qb  = (const float*)d_in[18];
  const float* ca_kw  = (const float*)d_in[19];
  const float* ca_kb  = (const float*)d_in[20];
  const float* ca_vw  = (const float*)d_in[21];
  const float* ca_vb  = (const float*)d_in[22];
  const float* ca_kiw = (const float*)d_in[23];
  const float* ca_kib = (const float*)d_in[24];
  const float* ca_viw = (const float*)d_in[25];
  const float* ca_vib = (const float*)d_in[26];
  const float* ca_ow  = (const float*)d_in[27];
  const float* ca_ob  = (const float*)d_in[28];
  const float* ca_nq  = (const float*)d_in[29];
  const float* ca_nk  = (const float*)d_in[30];
  const float* ca_nki = (const float*)d_in[31];
  const float* ffn_w1 = (const float*)d_in[32];
  const float* ffn_b1 = (const float*)d_in[33];
  const float* ffn_w2 = (const float*)d_in[34];
  const float* ffn_b2 = (const float*)d_in[35];

  char* ws = (char*)d_ws;
  size_t off = 0;
  auto alloc = [&](size_t bytes) -> void* {
    void* p = ws + off;
    off += (bytes + 255) & ~(size_t)255;
    return p;
  };
  float* e6f   = (float*)alloc((size_t)6 * DIM * 4);
  bf16* act_bf = (bf16*)alloc((size_t)SQ * DIM * 2);
  bf16* q_bf   = (bf16*)alloc((size_t)SQ * DIM * 2);
  bf16* k_bf   = (bf16*)alloc((size_t)SQ * DIM * 2);
  bf16* v_bf   = (bf16*)alloc((size_t)SQ * DIM * 2);
  // big0 shared region: qkvF [SQ,4608] f32 -> attn partials [3][SQ,DIM] f32
  //   -> projf [SQ,DIM] f32 -> cross partials -> y1 [SQ,FFN] bf16
  char* big0   = (char*)alloc((size_t)SQ * 3 * DIM * 4);
  float* xcur  = (float*)alloc((size_t)SQ * DIM * 4);
  bf16* wbig   = (bf16*)alloc((size_t)FFN * DIM * 2);     // qkvT / w1T / w2T (sequential reuse)
  bf16* wsm    = (bf16*)alloc((size_t)3 * DIM * DIM * 2); // owT/qT/kvT (sequential reuse)
  bf16* ctxt_bf = (bf16*)alloc((size_t)T5 * DIM * 2);
  bf16* ctxi_bf = (bf16*)alloc((size_t)IMGP * DIM * 2);
  float* ctxkvF = (float*)alloc((size_t)T5 * 2 * DIM * 4);
  float* ctxkivF = (float*)alloc((size_t)IMGP * 2 * DIM * 4);
  bf16* kt_bf  = (bf16*)alloc((size_t)T5 * DIM * 2);
  bf16* vt_bf  = (bf16*)alloc((size_t)T5 * DIM * 2);
  bf16* ki_bf  = (bf16*)alloc((size_t)IMGP * DIM * 2);
  bf16* vi_bf  = (bf16*)alloc((size_t)IMGP * DIM * 2);
  float* qkvB  = (float*)alloc((size_t)3 * DIM * 4);
  float* kvB   = (float*)alloc((size_t)2 * DIM * 4);
  float* kivB  = (float*)alloc((size_t)2 * DIM * 4);
  float* mlbuf = (float*)alloc((size_t)3 * NHEADS * SQ * 2 * 4);

  float* qkvF = (float*)big0;
  float* projf = (float*)big0;
  float* opart = (float*)big0;
  bf16* y1 = (bf16*)big0;
  float* pbuf = (float*)act_bf;  // FFN2 split-K partials (act/q/k/v dead by then)

  const float* e0 = e6f;
  const float* e1 = e6f + DIM;
  const float* e2 = e6f + 2 * DIM;
  const float* e3 = e6f + 3 * DIM;
  const float* e4 = e6f + 4 * DIM;
  const float* e5 = e6f + 5 * DIM;

  dim3 tblk(32, 8);

  prep_small_kernel<<<(6 * DIM + 255) / 256, 256, 0, stream>>>(
      modv, e, e6f, sa_qb, sa_kb, sa_vb, qkvB, ca_kb, ca_vb, kvB, ca_kib, ca_vib, kivB);

  // xs = LN(x)*(1+e1)+e0
  ln_mod_kernel<<<SQ, 256, 0, stream>>>(x, e1, e0, 1, act_bf);

  // ---- self attention: batched QKV ----
  transpose_w3_kernel<<<dim3(48, 48, 3), tblk, 0, stream>>>(sa_qw, sa_kw, sa_vw, wbig, DIM, DIM);
  gemm_db_kernel<128><<<dim3(3 * DIM / 128, SQ / 128), 256, 0, stream>>>(
      act_bf, wbig, qkvB, nullptr, nullptr, qkvF, nullptr, SQ, 3 * DIM, DIM, 0, 1);
  rms_rope_multi_kernel<<<dim3(SQ, 3), 256, 0, stream>>>(
      qkvF, 3 * DIM, 3, sa_nq, sa_nk, 2, 2, 0, freqs, q_bf, k_bf, v_bf);

  // K-split flash attention: 3 chunks of 1152 keys -> partials in big0 (qkvF dead)
  attn_kernel<<<dim3(SQ / 64, NHEADS, 3), 256, 0, stream>>>(
      q_bf, k_bf, v_bf, opart, mlbuf, SQ, SQ / 3, 0);
  attn_combine_kernel<<<SQ, 256, 0, stream>>>(opart, mlbuf, act_bf, 3, -1);

  // x = x + (attn @ sa_ow + sa_ob) * e2
  transpose_w3_kernel<<<dim3(48, 48, 1), tblk, 0, stream>>>(sa_ow, nullptr, nullptr, wsm, DIM, DIM);
  gemm_db_kernel<64><<<dim3(DIM / 128, SQ / 64), 256, 0, stream>>>(
      act_bf, wsm, sa_ob, e2, x, xcur, nullptr, SQ, DIM, DIM, 0, 1);

  // ---- cross attention ----
  ln_mod_kernel<<<SQ, 256, 0, stream>>>(xcur, norm3w, norm3b, 0, act_bf);

  transpose_w3_kernel<<<dim3(48, 48, 1), tblk, 0, stream>>>(ca_qw, nullptr, nullptr, wsm, DIM, DIM);
  gemm_db_kernel<64><<<dim3(DIM / 128, SQ / 64), 256, 0, stream>>>(
      act_bf, wsm, ca_qb, nullptr, nullptr, projf, nullptr, SQ, DIM, DIM, 0, 1);
  rms_rope_multi_kernel<<<dim3(SQ, 1), 256, 0, stream>>>(
      projf, DIM, 1, ca_nq, nullptr, 1, 0, 0, freqs, q_bf, nullptr, nullptr);

  prep_ctx_kernel<<<(T5 * DIM + 255) / 256, 256, 0, stream>>>(ctx, ctxt_bf, ctxi_bf);

  // txt K||V batched (M=512, N=3072)
  transpose_w3_kernel<<<dim3(48, 48, 2), tblk, 0, stream>>>(ca_kw, ca_vw, nullptr, wsm, DIM, DIM);
  gemm_db_kernel<64><<<dim3(2 * DIM / 128, T5 / 64), 256, 0, stream>>>(
      ctxt_bf, wsm, kvB, nullptr, nullptr, ctxkvF, nullptr, T5, 2 * DIM, DIM, 0, 1);
  rms_rope_multi_kernel<<<dim3(T5, 2), 256, 0, stream>>>(
      ctxkvF, 2 * DIM, 2, ca_nk, nullptr, 1, 0, 0, freqs, kt_bf, vt_bf, nullptr);

  // img KI||VI batched (M=384 padded, N=3072)
  transpose_w3_kernel<<<dim3(48, 48, 2), tblk, 0, stream>>>(ca_kiw, ca_viw, nullptr, wsm, DIM, DIM);
  gemm_db_kernel<64><<<dim3(2 * DIM / 128, IMGP / 64), 256, 0, stream>>>(
      ctxi_bf, wsm, kivB, nullptr, nullptr, ctxkivF, nullptr, IMGP, 2 * DIM, DIM, 0, 1);
  rms_rope_multi_kernel<<<dim3(IMGP, 2), 256, 0, stream>>>(
      ctxkivF, 2 * DIM, 2, ca_nki, nullptr, 1, 0, 0, freqs, ki_bf, vi_bf, nullptr);

  // cross attn: txt softmax as 2 K-splits (slots 0,1, merged); img softmax as
  // slot 2 (independent, ADDED in combine — matches reference semantics)
  attn_kernel<<<dim3(SQ / 64, NHEADS, 2), 256, 0, stream>>>(
      q_bf, kt_bf, vt_bf, opart, mlbuf, T5, T5 / 2, 0);
  attn_kernel<<<dim3(SQ / 64, NHEADS, 1), 256, 0, stream>>>(
      q_bf, ki_bf, vi_bf, opart, mlbuf, IMG, IMG, 2);
  attn_combine_kernel<<<SQ, 256, 0, stream>>>(opart, mlbuf, act_bf, 2, 2);

  // x = x + attn2 @ ca_ow + ca_ob
  transpose_w3_kernel<<<dim3(48, 48, 1), tblk, 0, stream>>>(ca_ow, nullptr, nullptr, wsm, DIM, DIM);
  gemm_db_kernel<64><<<dim3(DIM / 128, SQ / 64), 256, 0, stream>>>(
      act_bf, wsm, ca_ob, nullptr, xcur, xcur, nullptr, SQ, DIM, DIM, 0, 1);

  // ---- FFN ----
  ln_mod_kernel<<<SQ, 256, 0, stream>>>(xcur, e4, e3, 1, act_bf);

  transpose_w3_kernel<<<dim3(FFN / 32, 48, 1), tblk, 0, stream>>>(ffn_w1, nullptr, nullptr, wbig, DIM, FFN);
  gemm_db_kernel<128><<<dim3(FFN / 128, SQ / 128), 256, 0, stream>>>(
      act_bf, wbig, ffn_b1, nullptr, nullptr, nullptr, y1, SQ, FFN, DIM, 1, 1);

  transpose_w3_kernel<<<dim3(48, FFN / 32, 1), tblk, 0, stream>>>(ffn_w2, nullptr, nullptr, wbig, FFN, DIM);
  gemm_db_kernel<128><<<dim3(DIM / 128, SQ / 128, 2), 256, 0, stream>>>(
      y1, wbig, nullptr, nullptr, nullptr, pbuf, nullptr, SQ, DIM, FFN, 0, 2);
  ffn2_reduce_kernel<<<(SQ * DIM + 255) / 256, 256, 0, stream>>>(
      pbuf, ffn_b2, e5, xcur, (float*)d_out);
}

// Round 3
// 1243.873 us; speedup vs baseline: 1.1902x; 1.0673x over previous
//
#include <hip/hip_runtime.h>
#include <stdint.h>

#define DIM 1536
#define NHEADS 12
#define HD 128
#define FFN 8960
#define SQ 3456
#define T5 512
#define LCTX 769
#define IMG 257
#define IMGP 384
#define EPSL 1e-6f

typedef __bf16 bf16;
typedef __bf16 bf16x8 __attribute__((ext_vector_type(8)));
typedef float f32x4 __attribute__((ext_vector_type(4)));

__device__ inline bf16x8 zero_bf16x8() {
  bf16x8 v;
  for (int i = 0; i < 8; i++) v[i] = (bf16)0.0f;
  return v;
}

// async 16B global -> LDS. lds base must be wave-uniform; lane i lands at lds + i*16.
__device__ inline void glds16(const bf16* g, bf16* lds) {
  __builtin_amdgcn_global_load_lds(
      (const __attribute__((address_space(1))) void*)g,
      (__attribute__((address_space(3))) void*)lds, 16, 0, 0);
}

// rotate bf16x8 left by r elements: out[i] = v[(i+r)&7]. All compile-time vector
// subscripts (runtime subscripts spill to scratch); selects become v_cndmask,
// 1-element stage is v_alignbit.
__device__ inline bf16x8 rot8(bf16x8 v, int r) {
  union U { bf16x8 b; uint32_t d[4]; };
  U u; u.b = v;
  uint32_t e0 = (r & 4) ? u.d[2] : u.d[0], e1 = (r & 4) ? u.d[3] : u.d[1];
  uint32_t e2 = (r & 4) ? u.d[0] : u.d[2], e3 = (r & 4) ? u.d[1] : u.d[3];
  uint32_t f0 = (r & 2) ? e1 : e0, f1 = (r & 2) ? e2 : e1;
  uint32_t f2 = (r & 2) ? e3 : e2, f3 = (r & 2) ? e0 : e3;
  U o;
  o.d[0] = (r & 1) ? __builtin_amdgcn_alignbit(f1, f0, 16) : f0;
  o.d[1] = (r & 1) ? __builtin_amdgcn_alignbit(f2, f1, 16) : f1;
  o.d[2] = (r & 1) ? __builtin_amdgcn_alignbit(f3, f2, 16) : f2;
  o.d[3] = (r & 1) ? __builtin_amdgcn_alignbit(f0, f3, 16) : f3;
  return o.b;
}

// ---------------- small utility kernels ----------------

__global__ void prep_small_kernel(const float* __restrict__ modv, const float* __restrict__ e,
                                  float* __restrict__ e6f,
                                  const float* __restrict__ qb, const float* __restrict__ kb,
                                  const float* __restrict__ vb, float* __restrict__ qkvB,
                                  const float* __restrict__ ckb, const float* __restrict__ cvb,
                                  float* __restrict__ kvB,
                                  const float* __restrict__ kib, const float* __restrict__ vib,
                                  float* __restrict__ kivB) {
  int i = blockIdx.x * 256 + threadIdx.x;
  if (i < 6 * DIM) e6f[i] = modv[i] + e[i];
  if (i < DIM) {
    qkvB[i] = qb[i]; qkvB[i + DIM] = kb[i]; qkvB[i + 2 * DIM] = vb[i];
    kvB[i] = ckb[i]; kvB[i + DIM] = cvb[i];
    kivB[i] = kib[i]; kivB[i + DIM] = vib[i];
  }
}

// context -> bf16: txt rows 257..768 -> ctxt[512], img rows 0..256 -> ctxi[384] zero-padded
__global__ void prep_ctx_kernel(const float* __restrict__ ctx, bf16* __restrict__ ctxt,
                                bf16* __restrict__ ctxi) {
  int i = blockIdx.x * 256 + threadIdx.x;
  if (i < T5 * DIM) ctxt[i] = (bf16)ctx[(size_t)IMG * DIM + i];
  if (i < IMGP * DIM) {
    int r = i / DIM;
    ctxi[i] = (r < IMG) ? (bf16)ctx[i] : (bf16)0.0f;
  }
}

// transpose up to 3 weights W (K x N, f32) -> Wt (N x K, bf16), z selects source/dest slot.
__global__ void transpose_w3_kernel(const float* __restrict__ W0, const float* __restrict__ W1,
                                    const float* __restrict__ W2, bf16* __restrict__ Wt,
                                    int K, int N) {
  __shared__ float tile[32][33];
  const float* W = blockIdx.z == 0 ? W0 : (blockIdx.z == 1 ? W1 : W2);
  bf16* dst = Wt + (size_t)blockIdx.z * K * N;
  int n0 = blockIdx.x * 32, k0 = blockIdx.y * 32;
  int tx = threadIdx.x, ty = threadIdx.y;  // block (32,8)
  for (int i = ty; i < 32; i += 8)
    tile[i][tx] = W[(size_t)(k0 + i) * N + n0 + tx];
  __syncthreads();
  for (int i = ty; i < 32; i += 8)
    dst[(size_t)(n0 + i) * K + k0 + tx] = (bf16)tile[tx][i];
}

// block=256, two-value sum reduction broadcast to all threads
__device__ inline void block_reduce2(float& s1, float& s2) {
  __shared__ float buf[8];
  for (int off = 32; off; off >>= 1) {
    s1 += __shfl_down(s1, off, 64);
    s2 += __shfl_down(s2, off, 64);
  }
  int w = threadIdx.x >> 6;
  if ((threadIdx.x & 63) == 0) { buf[w] = s1; buf[w + 4] = s2; }
  __syncthreads();
  s1 = buf[0] + buf[1] + buf[2] + buf[3];
  s2 = buf[4] + buf[5] + buf[6] + buf[7];
  __syncthreads();
}

// y = LN(x) * (gamma (+1?)) + beta ; one block per row
__global__ __launch_bounds__(256) void ln_mod_kernel(
    const float* __restrict__ X, const float* __restrict__ gamma,
    const float* __restrict__ beta, int plus_one, bf16* __restrict__ out) {
  int r = blockIdx.x;
  const float* xr = X + (size_t)r * DIM;
  float v[6], s = 0.f, s2 = 0.f;
  for (int i = 0; i < 6; i++) {
    v[i] = xr[threadIdx.x + i * 256];
    s += v[i]; s2 += v[i] * v[i];
  }
  block_reduce2(s, s2);
  float mean = s * (1.0f / DIM);
  float var = s2 * (1.0f / DIM) - mean * mean;
  float rstd = rsqrtf(var + EPSL);
  float add1 = plus_one ? 1.0f : 0.0f;
  for (int i = 0; i < 6; i++) {
    int c = threadIdx.x + i * 256;
    out[(size_t)r * DIM + c] = (bf16)(((v[i] - mean) * rstd) * (gamma[c] + add1) + beta[c]);
  }
}

// fused per-row postprocess of a GEMM f32 output with row stride `istride`:
// blockIdx.y = section; per section: mode 0=cast, 1=rms, 2=rms+rope
__global__ __launch_bounds__(256) void rms_rope_multi_kernel(
    const float* __restrict__ X, int istride, int nsec,
    const float* __restrict__ nw0, const float* __restrict__ nw1,
    int mode0, int mode1, int mode2,
    const float* __restrict__ freqs,
    bf16* __restrict__ o0, bf16* __restrict__ o1, bf16* __restrict__ o2) {
  int sec = blockIdx.y;
  int r = blockIdx.x;
  const float* xr = X + (size_t)r * istride + sec * DIM;
  const float* nw = sec == 0 ? nw0 : nw1;
  bf16* out = (sec == 0 ? o0 : (sec == 1 ? o1 : o2)) + (size_t)r * DIM;
  int mode = sec == 0 ? mode0 : (sec == 1 ? mode1 : mode2);
  float v[6];
  for (int i = 0; i < 6; i++) v[i] = xr[threadIdx.x + i * 256];
  if (mode == 0) {
    for (int i = 0; i < 6; i++) out[threadIdx.x + i * 256] = (bf16)v[i];
    return;
  }
  float s2 = 0.f, dummy = 0.f;
  for (int i = 0; i < 6; i++) s2 += v[i] * v[i];
  block_reduce2(s2, dummy);
  float rms = rsqrtf(s2 * (1.0f / DIM) + EPSL);
  if (mode == 1) {
    for (int i = 0; i < 6; i++) {
      int c = threadIdx.x + i * 256;
      out[c] = (bf16)(v[i] * rms * nw[c]);
    }
  } else {
    int f = r / (18 * 24), rem = r % (18 * 24), hh = rem / 24, ww = rem % 24;
    for (int i = 0; i < 3; i++) {
      int p = threadIdx.x + i * 256;  // pair index
      int id = p & 63;
      int idx = id < 22 ? f : (id < 43 ? hh : ww);
      float th = freqs[idx * 64 + id];
      float cs = __cosf(th), sn = __sinf(th);
      float re = xr[2 * p] * rms * nw[2 * p];
      float im = xr[2 * p + 1] * rms * nw[2 * p + 1];
      out[2 * p]     = (bf16)(re * cs - im * sn);
      out[2 * p + 1] = (bf16)(re * sn + im * cs);
    }
  }
}

// FFN2 split-K reduce: out = xcur + (p0 + p1 + b2[col]) * e5[col]
__global__ void ffn2_reduce_kernel(const float* __restrict__ p, const float* __restrict__ b2,
                                   const float* __restrict__ e5, const float* __restrict__ xcur,
                                   float* __restrict__ out) {
  int i = blockIdx.x * 256 + threadIdx.x;
  if (i >= SQ * DIM) return;
  int col = i % DIM;
  out[i] = xcur[i] + (p[i] + p[i + (size_t)SQ * DIM] + b2[col]) * e5[col];
}

// ---------------- GEMM: C[M,N] = A[M,K](bf16) @ Wt[N,K]^T + epilogue ----------------
template <int BM>
__global__ __launch_bounds__(256) void gemm_db_kernel(
    const bf16* __restrict__ A, const bf16* __restrict__ Wt,
    const float* __restrict__ bias, const float* __restrict__ scalev,
    const float* __restrict__ resid, float* __restrict__ outF,
    bf16* __restrict__ outB, int M, int N, int K, int gelu, int ksplit) {
  constexpr int MI = BM / 32;
  constexpr int NAW = BM / 64;  // A glds per wave
  __shared__ bf16 As[2][BM * 32];
  __shared__ bf16 Bs[2][128 * 32];
  int tid = threadIdx.x;
  int tm0 = blockIdx.y * BM, tn0 = blockIdx.x * 128;
  int lane = tid & 63, wave = tid >> 6;
  int quad = lane >> 4, l16 = lane & 15;
  int mbase = (wave >> 1) * (BM / 2), nbase = (wave & 1) * 64;
  int lrow = lane >> 2, lcol = (lane & 3) * 8;
  int klen = K / ksplit;
  int kbeg = blockIdx.z * klen;

  const bf16* aP[NAW];
  const bf16* bP[2];
#pragma unroll
  for (int j = 0; j < NAW; j++) {
    int c = wave * NAW + j;
    aP[j] = A + (size_t)(tm0 + c * 16 + lrow) * K + kbeg + lcol;
  }
#pragma unroll
  for (int j = 0; j < 2; j++) {
    int c = wave * 2 + j;
    bP[j] = Wt + (size_t)(tn0 + c * 16 + lrow) * K + kbeg + lcol;
  }

  f32x4 acc[MI][4];
#pragma unroll
  for (int mi = 0; mi < MI; mi++)
    for (int ni = 0; ni < 4; ni++)
      for (int rr = 0; rr < 4; rr++) acc[mi][ni][rr] = 0.0f;

  auto stage = [&](int buf) {
#pragma unroll
    for (int j = 0; j < NAW; j++) {
      glds16(aP[j], &As[buf][(wave * NAW + j) * 512]);
      aP[j] += 32;
    }
#pragma unroll
    for (int j = 0; j < 2; j++) {
      glds16(bP[j], &Bs[buf][(wave * 2 + j) * 512]);
      bP[j] += 32;
    }
  };

  int niter = klen / 32;
  stage(0);
  int cur = 0;
  for (int it = 0; it < niter; it++) {
    __syncthreads();               // drains vmcnt: tile `cur` resident in LDS
    if (it + 1 < niter) stage(cur ^ 1);  // prefetch overlaps compute below
    bf16x8 af[MI], bfr[4];
#pragma unroll
    for (int mi = 0; mi < MI; mi++)
      af[mi] = *(bf16x8*)&As[cur][(mbase + mi * 16 + l16) * 32 + quad * 8];
#pragma unroll
    for (int ni = 0; ni < 4; ni++)
      bfr[ni] = *(bf16x8*)&Bs[cur][(nbase + ni * 16 + l16) * 32 + quad * 8];
#pragma unroll
    for (int mi = 0; mi < MI; mi++)
#pragma unroll
      for (int ni = 0; ni < 4; ni++)
        acc[mi][ni] = __builtin_amdgcn_mfma_f32_16x16x32_bf16(af[mi], bfr[ni], acc[mi][ni], 0, 0, 0);
    cur ^= 1;
  }

  if (ksplit > 1) {
    float* po = outF + (size_t)blockIdx.z * M * N;
#pragma unroll
    for (int mi = 0; mi < MI; mi++) {
      int rbase = tm0 + mbase + mi * 16 + quad * 4;
#pragma unroll
      for (int ni = 0; ni < 4; ni++) {
        int col = tn0 + nbase + ni * 16 + l16;
        for (int rr = 0; rr < 4; rr++)
          po[(size_t)(rbase + rr) * N + col] = acc[mi][ni][rr];
      }
    }
    return;
  }

#pragma unroll
  for (int mi = 0; mi < MI; mi++) {
    int rbase = tm0 + mbase + mi * 16 + quad * 4;
#pragma unroll
    for (int ni = 0; ni < 4; ni++) {
      int col = tn0 + nbase + ni * 16 + l16;
      float b = bias ? bias[col] : 0.0f;
      float sc = scalev ? scalev[col] : 1.0f;
      for (int rr = 0; rr < 4; rr++) {
        int row = rbase + rr;
        float t = acc[mi][ni][rr] + b;
        if (gelu) {
          float z = t;
          float u = 0.7978845608028654f * (z + 0.044715f * z * z * z);
          t = z / (1.0f + __expf(-2.0f * u));  // == 0.5z(1+tanh(u))
        }
        t *= sc;
        size_t idx = (size_t)row * N + col;
        if (resid) t += resid[idx];
        if (outF) outF[idx] = t;
        else outB[idx] = (bf16)t;
      }
    }
  }
}

// ---------------- Flash attention, K-split partials, KVBLK=64 ----------------
// Each block: 64 q-rows x one head x one K-chunk. KVBLK=64 halves per-tile fixed
// costs vs 32. Serial-chain removal (the round-2 VALUBusy=48% diagnosis):
//  - row-sum of P comes from an extra MFMA with a ones-B fragment (output layout
//    lands sum[r] in exactly the right lane/reg) -> no shfl sum chains.
//  - defer-max (T13): per-lane local max + one __all ballot; the 4-deep shfl max
//    chains + o-rescale run only when max grows >8 (first tile, rarely after).
// Conflict-free layouts (all derived to b128-minimum): Ks[64][136] vector writes,
// rotated scalar V-transpose writes (rot = (2*scolc+(srow&1))&7), Ps[4][16][72]
// with row-XOR-16-elem swizzle on both write and read sides.
__global__ __launch_bounds__(256) void attn_kernel(
    const bf16* __restrict__ Q, const bf16* __restrict__ Kb, const bf16* __restrict__ Vb,
    float* __restrict__ Opart, float* __restrict__ mlb,
    int L, int kchunk, int zoff) {
  __shared__ bf16 Ks[64][136];
  __shared__ bf16 Vts[128][72];
  __shared__ bf16 Ps[4][16][72];

  // XCD-contiguity swizzle (bijective when nwg % 8 == 0; all our grids are).
  int nwg = gridDim.x * gridDim.y * gridDim.z;
  int flat = blockIdx.x + gridDim.x * (blockIdx.y + gridDim.y * blockIdx.z);
  if ((nwg & 7) == 0) flat = (flat & 7) * (nwg >> 3) + (flat >> 3);
  int bx = flat % gridDim.x;
  int rest = flat / gridDim.x;
  int hb = rest % gridDim.y;
  int bz = rest / gridDim.y;

  int tid = threadIdx.x;
  int q0 = bx * 64;
  int zabs = zoff + bz;
  int kbeg = bz * kchunk;
  int kend = min(L, kbeg + kchunk);
  int klen = kend - kbeg;
  int lane = tid & 63, wave = tid >> 6;
  int quad = lane >> 4, l16 = lane & 15;
  int qrow = q0 + wave * 16 + l16;

  bf16x8 qf[4];
#pragma unroll
  for (int c = 0; c < 4; c++)
    qf[c] = *(const bf16x8*)(Q + (size_t)qrow * DIM + hb * HD + c * 32 + quad * 8);

  bf16x8 onesv;
#pragma unroll
  for (int i = 0; i < 8; i++) onesv[i] = (bf16)1.0f;

  f32x4 o[8];
#pragma unroll
  for (int ff = 0; ff < 8; ff++)
    for (int rr = 0; rr < 4; rr++) o[ff][rr] = 0.0f;
  float m_i[4], l_i[4];
#pragma unroll
  for (int r = 0; r < 4; r++) { m_i[r] = -1e30f; l_i[r] = 0.0f; }
  const float sc = 0.08838834764831845f;  // 1/sqrt(128)

  // staging: 4 threads per key row; each loads 4x16B (32 cols) of K and V
  int srow = tid >> 2, scolc = tid & 3;
  int rot = (2 * scolc + (srow & 1)) & 7;
  int nt = (klen + 63) / 64;

  const bf16* kp0 = Kb + (size_t)(kbeg + srow) * DIM + hb * HD + scolc * 8;
  const bf16* vp0 = Vb + (size_t)(kbeg + srow) * DIM + hb * HD + scolc * 8;

  bf16x8 kreg[4], vreg[4];
  if (srow < klen) {
#pragma unroll
    for (int c = 0; c < 4; c++) {
      kreg[c] = *(const bf16x8*)(kp0 + c * 32);
      vreg[c] = *(const bf16x8*)(vp0 + c * 32);
    }
  } else {
#pragma unroll
    for (int c = 0; c < 4; c++) { kreg[c] = zero_bf16x8(); vreg[c] = zero_bf16x8(); }
  }

  for (int kt = 0; kt < nt; kt++) {
    __syncthreads();  // prev tile's LDS readers done
#pragma unroll
    for (int c = 0; c < 4; c++)
      *(bf16x8*)&Ks[srow][scolc * 8 + c * 32] = kreg[c];
#pragma unroll
    for (int c = 0; c < 4; c++) {
      bf16x8 rv = rot8(vreg[c], rot);
      int v0 = scolc * 8 + c * 32;
#pragma unroll
      for (int i = 0; i < 8; i++) {
        int jj = (i + rot) & 7;
        Vts[v0 + jj][srow] = rv[i];
      }
    }
    // prefetch next tile into registers; consumed after next loop-top barrier
    if (kt + 1 < nt) {
      int key = (kt + 1) * 64 + srow;
      const bf16* kp = kp0 + (size_t)(kt + 1) * 64 * DIM;
      const bf16* vp = vp0 + (size_t)(kt + 1) * 64 * DIM;
      if (key < klen) {
#pragma unroll
        for (int c = 0; c < 4; c++) {
          kreg[c] = *(const bf16x8*)(kp + c * 32);
          vreg[c] = *(const bf16x8*)(vp + c * 32);
        }
      } else {
#pragma unroll
        for (int c = 0; c < 4; c++) { kreg[c] = zero_bf16x8(); vreg[c] = zero_bf16x8(); }
      }
    }
    __syncthreads();  // staged tile visible

    f32x4 sfr[4];
    __builtin_amdgcn_s_setprio(1);
#pragma unroll
    for (int nf = 0; nf < 4; nf++) {
      f32x4 a;
      for (int rr = 0; rr < 4; rr++) a[rr] = 0.0f;
#pragma unroll
      for (int c = 0; c < 4; c++) {
        bf16x8 kf = *(bf16x8*)&Ks[nf * 16 + l16][c * 32 + quad * 8];
        a = __builtin_amdgcn_mfma_f32_16x16x32_bf16(qf[c], kf, a, 0, 0, 0);
      }
      sfr[nf] = a;
    }
    __builtin_amdgcn_s_setprio(0);

#pragma unroll
    for (int nf = 0; nf < 4; nf++) {
      int colg = kt * 64 + nf * 16 + l16;
      bool valid = colg < klen;
#pragma unroll
      for (int r = 0; r < 4; r++)
        sfr[nf][r] = valid ? sfr[nf][r] * sc : -1e30f;
    }

    // defer-max: local per-lane max + one ballot; full chain only when needed
    float lmax[4];
#pragma unroll
    for (int r = 0; r < 4; r++)
      lmax[r] = fmaxf(fmaxf(sfr[0][r], sfr[1][r]), fmaxf(sfr[2][r], sfr[3][r]));
    int ok = (lmax[0] <= m_i[0] + 8.0f) & (lmax[1] <= m_i[1] + 8.0f) &
             (lmax[2] <= m_i[2] + 8.0f) & (lmax[3] <= m_i[3] + 8.0f);
    if (!__all(ok)) {
#pragma unroll
      for (int r = 0; r < 4; r++) {
        float t = lmax[r];
#pragma unroll
        for (int off = 1; off < 16; off <<= 1) t = fmaxf(t, __shfl_xor(t, off, 64));
        float mnew = fmaxf(m_i[r], t);
        float alpha = __expf(m_i[r] - mnew);
        m_i[r] = mnew;
        l_i[r] *= alpha;
#pragma unroll
        for (int ff = 0; ff < 8; ff++) o[ff][r] *= alpha;
      }
    }

    // p = exp(s - m) (bounded by e^8), write to Ps with row-XOR swizzle
#pragma unroll
    for (int r = 0; r < 4; r++) {
      char* prow = (char*)&Ps[wave][quad * 4 + r][0];
      int swzW = ((quad >> 1) & 1) << 5;  // f(row)= (row>>3 &1)*32 bytes
#pragma unroll
      for (int nf = 0; nf < 4; nf++) {
        float p = __expf(sfr[nf][r] - m_i[r]);
        *(bf16*)(prow + (((nf * 16 + l16) * 2) ^ swzW)) = (bf16)p;
      }
    }
    // read P fragments (row = l16 -> XOR key = (l16>>3 &1)*32 bytes)
    int swzR = ((l16 >> 3) & 1) << 5;
    bf16x8 pf[2];
#pragma unroll
    for (int ks = 0; ks < 2; ks++)
      pf[ks] = *(bf16x8*)((char*)&Ps[wave][l16][0] + (((ks * 32 + quad * 8) * 2) ^ swzR));

    __builtin_amdgcn_s_setprio(1);
    // l-sum via MFMA with ones-B: D[row,*] = sum_k P[row,k]; lands in l_i layout
    f32x4 ld;
    for (int rr = 0; rr < 4; rr++) ld[rr] = 0.0f;
    ld = __builtin_amdgcn_mfma_f32_16x16x32_bf16(pf[0], onesv, ld, 0, 0, 0);
    ld = __builtin_amdgcn_mfma_f32_16x16x32_bf16(pf[1], onesv, ld, 0, 0, 0);
#pragma unroll
    for (int ff = 0; ff < 8; ff++) {
#pragma unroll
      for (int ks = 0; ks < 2; ks++) {
        bf16x8 vf = *(bf16x8*)&Vts[ff * 16 + l16][ks * 32 + quad * 8];
        o[ff] = __builtin_amdgcn_mfma_f32_16x16x32_bf16(pf[ks], vf, o[ff], 0, 0, 0);
      }
    }
    __builtin_amdgcn_s_setprio(0);
#pragma unroll
    for (int r = 0; r < 4; r++) l_i[r] += ld[r];
  }

  float* po = Opart + (size_t)zabs * SQ * DIM;
#pragma unroll
  for (int r = 0; r < 4; r++) {
    float inv = 1.0f / l_i[r];
#pragma unroll
    for (int ff = 0; ff < 8; ff++) o[ff][r] *= inv;
  }
#pragma unroll
  for (int ff = 0; ff < 8; ff++) {
#pragma unroll
    for (int r = 0; r < 4; r++) {
      int row = q0 + wave * 16 + quad * 4 + r;
      int col = hb * HD + ff * 16 + l16;
      po[(size_t)row * DIM + col] = o[ff][r];
    }
  }
  if (l16 == 0) {
#pragma unroll
    for (int r = 0; r < 4; r++) {
      int row = q0 + wave * 16 + quad * 4 + r;
      size_t mi = (((size_t)zabs * NHEADS + hb) * SQ + row) * 2;
      mlb[mi] = m_i[r];
      mlb[mi + 1] = l_i[r];
    }
  }
}

// Combine partial attention outputs.
// Slots [0, nmerge) are flash-decoding partials of ONE softmax -> merged with
// weights w_z = l_z*exp(m_z-M)/sum. If addslot >= 0, that slot is a SEPARATE,
// already-normalized attention output that is ADDED (reference cross-attn is
// softmax(txt) + softmax(img), NOT a softmax over the union).
__global__ __launch_bounds__(256) void attn_combine_kernel(
    const float* __restrict__ Op, const float* __restrict__ mlb,
    bf16* __restrict__ out, int nmerge, int addslot) {
  int row = blockIdx.x;
  __shared__ float wsh[3 * NHEADS];
  int t = threadIdx.x;
  if (t < NHEADS) {
    float m[3], l[3];
    for (int z = 0; z < 3; z++) {
      if (z < nmerge) {
        size_t b = (((size_t)z * NHEADS + t) * SQ + row) * 2;
        m[z] = mlb[b]; l[z] = mlb[b + 1];
      } else {
        m[z] = -1e30f; l[z] = 0.0f;
      }
    }
    float M = fmaxf(m[0], fmaxf(m[1], m[2]));
    float w0 = l[0] * __expf(m[0] - M);
    float w1 = l[1] * __expf(m[1] - M);
    float w2 = l[2] * __expf(m[2] - M);
    float inv = 1.0f / (w0 + w1 + w2);
    wsh[t] = w0 * inv;
    wsh[NHEADS + t] = w1 * inv;
    wsh[2 * NHEADS + t] = w2 * inv;
  }
  __syncthreads();
#pragma unroll
  for (int i = 0; i < 6; i++) {
    int c = t + i * 256;
    int h = c >> 7;
    float acc = wsh[h] * Op[((size_t)0 * SQ + row) * DIM + c];
    if (nmerge > 1) acc += wsh[NHEADS + h] * Op[((size_t)1 * SQ + row) * DIM + c];
    if (nmerge > 2) acc += wsh[2 * NHEADS + h] * Op[((size_t)2 * SQ + row) * DIM + c];
    if (addslot >= 0) acc += Op[((size_t)addslot * SQ + row) * DIM + c];
    out[(size_t)row * DIM + c] = (bf16)acc;
  }
}

// ---------------- host orchestration ----------------

extern "C" void kernel_launch(void* const* d_in, const int* in_sizes, int n_in,
                              void* d_out, int out_size, void* d_ws, size_t ws_size,
                              hipStream_t stream) {
  const float* x      = (const float*)d_in[0];
  const float* e      = (const float*)d_in[1];
  const float* ctx    = (const float*)d_in[2];
  const float* freqs  = (const float*)d_in[3];
  const float* modv   = (const float*)d_in[4];
  const float* sa_qw  = (const float*)d_in[5];
  const float* sa_qb  = (const float*)d_in[6];
  const float* sa_kw  = (const float*)d_in[7];
  const float* sa_kb  = (const float*)d_in[8];
  const float* sa_vw  = (const float*)d_in[9];
  const float* sa_vb  = (const float*)d_in[10];
  const float* sa_ow  = (const float*)d_in[11];
  const float* sa_ob  = (const float*)d_in[12];
  const float* sa_nq  = (const float*)d_in[13];
  const float* sa_nk  = (const float*)d_in[14];
  const float* norm3w = (const float*)d_in[15];
  const float* norm3b = (const float*)d_in[16];
  const float* ca_qw  = (const float*)d_in[17];
  const float* ca_qb  = (const float*)d_in[18];
  const float* ca_kw  = (const float*)d_in[19];
  const float* ca_kb  = (const float*)d_in[20];
  const float* ca_vw  = (const float*)d_in[21];
  const float* ca_vb  = (const float*)d_in[22];
  const float* ca_kiw = (const float*)d_in[23];
  const float* ca_kib = (const float*)d_in[24];
  const float* ca_viw = (const float*)d_in[25];
  const float* ca_vib = (const float*)d_in[26];
  const float* ca_ow  = (const float*)d_in[27];
  const float* ca_ob  = (const float*)d_in[28];
  const float* ca_nq  = (const float*)d_in[29];
  const float* ca_nk  = (const float*)d_in[30];
  const float* ca_nki = (const float*)d_in[31];
  const float* ffn_w1 = (const float*)d_in[32];
  const float* ffn_b1 = (const float*)d_in[33];
  const float* ffn_w2 = (const float*)d_in[34];
  const float* ffn_b2 = (const float*)d_in[35];

  char* ws = (char*)d_ws;
  size_t off = 0;
  auto alloc = [&](size_t bytes) -> void* {
    void* p = ws + off;
    off += (bytes + 255) & ~(size_t)255;
    return p;
  };
  float* e6f   = (float*)alloc((size_t)6 * DIM * 4);
  bf16* act_bf = (bf16*)alloc((size_t)SQ * DIM * 2);
  bf16* q_bf   = (bf16*)alloc((size_t)SQ * DIM * 2);
  bf16* k_bf   = (bf16*)alloc((size_t)SQ * DIM * 2);
  bf16* v_bf   = (bf16*)alloc((size_t)SQ * DIM * 2);
  // big0 shared region: qkvF [SQ,4608] f32 -> attn partials [3][SQ,DIM] f32
  //   -> projf [SQ,DIM] f32 -> cross partials -> y1 [SQ,FFN] bf16
  char* big0   = (char*)alloc((size_t)SQ * 3 * DIM * 4);
  float* xcur  = (float*)alloc((size_t)SQ * DIM * 4);
  bf16* wbig   = (bf16*)alloc((size_t)FFN * DIM * 2);     // qkvT / w1T / w2T (sequential reuse)
  bf16* wsm    = (bf16*)alloc((size_t)3 * DIM * DIM * 2); // owT/qT/kvT (sequential reuse)
  bf16* ctxt_bf = (bf16*)alloc((size_t)T5 * DIM * 2);
  bf16* ctxi_bf = (bf16*)alloc((size_t)IMGP * DIM * 2);
  float* ctxkvF = (float*)alloc((size_t)T5 * 2 * DIM * 4);
  float* ctxkivF = (float*)alloc((size_t)IMGP * 2 * DIM * 4);
  bf16* kt_bf  = (bf16*)alloc((size_t)T5 * DIM * 2);
  bf16* vt_bf  = (bf16*)alloc((size_t)T5 * DIM * 2);
  bf16* ki_bf  = (bf16*)alloc((size_t)IMGP * DIM * 2);
  bf16* vi_bf  = (bf16*)alloc((size_t)IMGP * DIM * 2);
  float* qkvB  = (float*)alloc((size_t)3 * DIM * 4);
  float* kvB   = (float*)alloc((size_t)2 * DIM * 4);
  float* kivB  = (float*)alloc((size_t)2 * DIM * 4);
  float* mlbuf = (float*)alloc((size_t)3 * NHEADS * SQ * 2 * 4);

  float* qkvF = (float*)big0;
  float* projf = (float*)big0;
  float* opart = (float*)big0;
  bf16* y1 = (bf16*)big0;
  float* pbuf = (float*)act_bf;  // FFN2 split-K partials (act/q/k/v dead by then)

  const float* e0 = e6f;
  const float* e1 = e6f + DIM;
  const float* e2 = e6f + 2 * DIM;
  const float* e3 = e6f + 3 * DIM;
  const float* e4 = e6f + 4 * DIM;
  const float* e5 = e6f + 5 * DIM;

  dim3 tblk(32, 8);

  prep_small_kernel<<<(6 * DIM + 255) / 256, 256, 0, stream>>>(
      modv, e, e6f, sa_qb, sa_kb, sa_vb, qkvB, ca_kb, ca_vb, kvB, ca_kib, ca_vib, kivB);

  // xs = LN(x)*(1+e1)+e0
  ln_mod_kernel<<<SQ, 256, 0, stream>>>(x, e1, e0, 1, act_bf);

  // ---- self attention: batched QKV ----
  transpose_w3_kernel<<<dim3(48, 48, 3), tblk, 0, stream>>>(sa_qw, sa_kw, sa_vw, wbig, DIM, DIM);
  gemm_db_kernel<128><<<dim3(3 * DIM / 128, SQ / 128), 256, 0, stream>>>(
      act_bf, wbig, qkvB, nullptr, nullptr, qkvF, nullptr, SQ, 3 * DIM, DIM, 0, 1);
  rms_rope_multi_kernel<<<dim3(SQ, 3), 256, 0, stream>>>(
      qkvF, 3 * DIM, 3, sa_nq, sa_nk, 2, 2, 0, freqs, q_bf, k_bf, v_bf);

  // K-split flash attention: 3 chunks of 1152 keys -> partials in big0 (qkvF dead)
  attn_kernel<<<dim3(SQ / 64, NHEADS, 3), 256, 0, stream>>>(
      q_bf, k_bf, v_bf, opart, mlbuf, SQ, SQ / 3, 0);
  attn_combine_kernel<<<SQ, 256, 0, stream>>>(opart, mlbuf, act_bf, 3, -1);

  // x = x + (attn @ sa_ow + sa_ob) * e2
  transpose_w3_kernel<<<dim3(48, 48, 1), tblk, 0, stream>>>(sa_ow, nullptr, nullptr, wsm, DIM, DIM);
  gemm_db_kernel<64><<<dim3(DIM / 128, SQ / 64), 256, 0, stream>>>(
      act_bf, wsm, sa_ob, e2, x, xcur, nullptr, SQ, DIM, DIM, 0, 1);

  // ---- cross attention ----
  ln_mod_kernel<<<SQ, 256, 0, stream>>>(xcur, norm3w, norm3b, 0, act_bf);

  transpose_w3_kernel<<<dim3(48, 48, 1), tblk, 0, stream>>>(ca_qw, nullptr, nullptr, wsm, DIM, DIM);
  gemm_db_kernel<64><<<dim3(DIM / 128, SQ / 64), 256, 0, stream>>>(
      act_bf, wsm, ca_qb, nullptr, nullptr, projf, nullptr, SQ, DIM, DIM, 0, 1);
  rms_rope_multi_kernel<<<dim3(SQ, 1), 256, 0, stream>>>(
      projf, DIM, 1, ca_nq, nullptr, 1, 0, 0, freqs, q_bf, nullptr, nullptr);

  prep_ctx_kernel<<<(T5 * DIM + 255) / 256, 256, 0, stream>>>(ctx, ctxt_bf, ctxi_bf);

  // txt K||V batched (M=512, N=3072)
  transpose_w3_kernel<<<dim3(48, 48, 2), tblk, 0, stream>>>(ca_kw, ca_vw, nullptr, wsm, DIM, DIM);
  gemm_db_kernel<64><<<dim3(2 * DIM / 128, T5 / 64), 256, 0, stream>>>(
      ctxt_bf, wsm, kvB, nullptr, nullptr, ctxkvF, nullptr, T5, 2 * DIM, DIM, 0, 1);
  rms_rope_multi_kernel<<<dim3(T5, 2), 256, 0, stream>>>(
      ctxkvF, 2 * DIM, 2, ca_nk, nullptr, 1, 0, 0, freqs, kt_bf, vt_bf, nullptr);

  // img KI||VI batched (M=384 padded, N=3072)
  transpose_w3_kernel<<<dim3(48, 48, 2), tblk, 0, stream>>>(ca_kiw, ca_viw, nullptr, wsm, DIM, DIM);
  gemm_db_kernel<64><<<dim3(2 * DIM / 128, IMGP / 64), 256, 0, stream>>>(
      ctxi_bf, wsm, kivB, nullptr, nullptr, ctxkivF, nullptr, IMGP, 2 * DIM, DIM, 0, 1);
  rms_rope_multi_kernel<<<dim3(IMGP, 2), 256, 0, stream>>>(
      ctxkivF, 2 * DIM, 2, ca_nki, nullptr, 1, 0, 0, freqs, ki_bf, vi_bf, nullptr);

  // cross attn: txt softmax as 2 K-splits (slots 0,1, merged); img softmax as
  // slot 2 (independent, ADDED in combine — matches reference semantics)
  attn_kernel<<<dim3(SQ / 64, NHEADS, 2), 256, 0, stream>>>(
      q_bf, kt_bf, vt_bf, opart, mlbuf, T5, T5 / 2, 0);
  attn_kernel<<<dim3(SQ / 64, NHEADS, 1), 256, 0, stream>>>(
      q_bf, ki_bf, vi_bf, opart, mlbuf, IMG, IMG, 2);
  attn_combine_kernel<<<SQ, 256, 0, stream>>>(opart, mlbuf, act_bf, 2, 2);

  // x = x + attn2 @ ca_ow + ca_ob
  transpose_w3_kernel<<<dim3(48, 48, 1), tblk, 0, stream>>>(ca_ow, nullptr, nullptr, wsm, DIM, DIM);
  gemm_db_kernel<64><<<dim3(DIM / 128, SQ / 64), 256, 0, stream>>>(
      act_bf, wsm, ca_ob, nullptr, xcur, xcur, nullptr, SQ, DIM, DIM, 0, 1);

  // ---- FFN ----
  ln_mod_kernel<<<SQ, 256, 0, stream>>>(xcur, e4, e3, 1, act_bf);

  transpose_w3_kernel<<<dim3(FFN / 32, 48, 1), tblk, 0, stream>>>(ffn_w1, nullptr, nullptr, wbig, DIM, FFN);
  gemm_db_kernel<128><<<dim3(FFN / 128, SQ / 128), 256, 0, stream>>>(
      act_bf, wbig, ffn_b1, nullptr, nullptr, nullptr, y1, SQ, FFN, DIM, 1, 1);

  transpose_w3_kernel<<<dim3(48, FFN / 32, 1), tblk, 0, stream>>>(ffn_w2, nullptr, nullptr, wbig, FFN, DIM);
  gemm_db_kernel<128><<<dim3(DIM / 128, SQ / 128, 2), 256, 0, stream>>>(
      y1, wbig, nullptr, nullptr, nullptr, pbuf, nullptr, SQ, DIM, FFN, 0, 2);
  ffn2_reduce_kernel<<<(SQ * DIM + 255) / 256, 256, 0, stream>>>(
      pbuf, ffn_b2, e5, xcur, (float*)d_out);
}